// Round 5
// baseline (403.802 us; speedup 1.0000x reference)
//
#include <hip/hip_runtime.h>

// ---------------------------------------------------------------------------
// MultiheadAttention fwd, MI355X gfx950.
// B=2, S=2048, D=1024, H=16, DH=64.  fp16 compute, fp32 MFMA acc.
// R5: R4 structure with the split-K lsum bug fixed: denominator is per
// (row, head) -> lsum[2][4096][16]; k_proj applies per-head lv (head == kt).
// ---------------------------------------------------------------------------

typedef _Float16 f16;
typedef __attribute__((ext_vector_type(8))) _Float16 f16x8;
typedef __attribute__((ext_vector_type(4))) _Float16 f16x4;
typedef __attribute__((ext_vector_type(4))) float f32x4;
typedef unsigned long long u64;
typedef unsigned int u32;

#define MFMA16 __builtin_amdgcn_mfma_f32_16x16x32_f16

// ---------------- kernel 1: fused QKV GEMM + mask packing ------------------
// blocks [0,768): C[4096][1024] = X W^T + bias (fp32 in, f16 staged)
//   which 0:Q / 1:K -> [B][H][S][64] via LDS bounce; 2: V -> [B][H][64][S].
// blocks [768,1792): pack attn_mask [2][2048][2048] i32 -> bits [4096][32] u64
__global__ __launch_bounds__(256) void k_qkvm(
    const float* __restrict__ embed, const float* __restrict__ keyf,
    const int* __restrict__ mask,
    const float* __restrict__ wq, const float* __restrict__ wk,
    const float* __restrict__ wv,
    const float* __restrict__ bq, const float* __restrict__ bk,
    const float* __restrict__ bv,
    f16* __restrict__ Qh, f16* __restrict__ Kh, f16* __restrict__ Vt,
    u64* __restrict__ bits)
{
    int bid = blockIdx.x;
    int tid = threadIdx.x;

    if (bid >= 768) {
        // ---- mask packing: 4 waves/block, one 2048-row per wave ----
        int gw = (bid - 768) * 4 + (tid >> 6);   // 0..4095
        int lane = tid & 63;
        const int* row = mask + (long)gw * 2048;
        u64* outb = bits + (long)gw * 32;
        #pragma unroll 4
        for (int c = 0; c < 32; ++c) {
            int v = row[c * 64 + lane];
            u64 bm = __ballot(v != 0);
            if (lane == 0) outb[c] = bm;
        }
        return;
    }

    int which = bid >> 8;
    int rr_ = bid & 255;
    int tm = rr_ >> 3, tn = rr_ & 7;
    const float* Xf = (which == 0) ? embed : keyf;
    const float* Wf = (which == 0) ? wq : (which == 1) ? wk : wv;
    const float* bias = (which == 0) ? bq : (which == 1) ? bk : bv;

    __shared__ f16 smem[128 * 136];
    f16* la = smem;
    f16* lb = smem + 128 * 64;

    int lane = tid & 63, wid = tid >> 6;
    int wr = wid >> 1, wc = wid & 1;
    int lm = lane & 15, qd = lane >> 4;

    f32x4 acc[4][4];
    #pragma unroll
    for (int i = 0; i < 4; i++)
        #pragma unroll
        for (int j = 0; j < 4; j++) acc[i][j] = (f32x4)0.0f;

    int m0 = tm * 128, n0 = tn * 128;

    for (int kt = 0; kt < 16; ++kt) {
        int k0 = kt * 64;
        __syncthreads();
        #pragma unroll
        for (int t = 0; t < 4; ++t) {
            int cid = tid + t * 256;          // 0..1023 8-elem chunks
            int row = cid >> 3;
            int cg = cid & 7;
            int sw = cg ^ (row & 7);
            {
                const float4* s4 = (const float4*)&Xf[(long)(m0 + row) * 1024 + k0 + cg * 8];
                float4 a = s4[0], b2 = s4[1];
                f16x8 o;
                o[0]=(f16)a.x; o[1]=(f16)a.y; o[2]=(f16)a.z; o[3]=(f16)a.w;
                o[4]=(f16)b2.x; o[5]=(f16)b2.y; o[6]=(f16)b2.z; o[7]=(f16)b2.w;
                *(f16x8*)&la[row * 64 + sw * 8] = o;
            }
            {
                const float4* s4 = (const float4*)&Wf[(long)(n0 + row) * 1024 + k0 + cg * 8];
                float4 a = s4[0], b2 = s4[1];
                f16x8 o;
                o[0]=(f16)a.x; o[1]=(f16)a.y; o[2]=(f16)a.z; o[3]=(f16)a.w;
                o[4]=(f16)b2.x; o[5]=(f16)b2.y; o[6]=(f16)b2.z; o[7]=(f16)b2.w;
                *(f16x8*)&lb[row * 64 + sw * 8] = o;
            }
        }
        __syncthreads();
        #pragma unroll
        for (int ks = 0; ks < 2; ++ks) {
            f16x8 af[4], bfr[4];
            #pragma unroll
            for (int i = 0; i < 4; i++) {
                int m = 64 * wr + 16 * i + lm;
                int g = (ks * 4 + qd) ^ (m & 7);
                af[i] = *(const f16x8*)&la[m * 64 + g * 8];
                int n = 64 * wc + 16 * i + lm;
                int g2 = (ks * 4 + qd) ^ (n & 7);
                bfr[i] = *(const f16x8*)&lb[n * 64 + g2 * 8];
            }
            #pragma unroll
            for (int i = 0; i < 4; i++)
                #pragma unroll
                for (int j = 0; j < 4; j++)
                    acc[i][j] = MFMA16(af[i], bfr[j], acc[i][j], 0, 0, 0);
        }
    }

    if (which == 2) {
        // V: direct transposed store [B][H][64][S], b64 along s
        #pragma unroll
        for (int j = 0; j < 4; j++) {
            int n = n0 + 64 * wc + 16 * j + lm;
            float bb = bias[n];
            int h = n >> 6, d = n & 63;
            #pragma unroll
            for (int i = 0; i < 4; i++) {
                int mbase = m0 + 64 * wr + 16 * i + 4 * qd;
                f16x4 pk;
                #pragma unroll
                for (int r = 0; r < 4; ++r) pk[r] = (f16)(acc[i][j][r] + bb);
                int b = mbase >> 11, s = mbase & 2047;
                *(f16x4*)&Vt[(((long)(b * 16 + h)) * 64 + d) * 2048 + s] = pk;
            }
        }
    } else {
        // Q/K: LDS bounce -> coalesced b128 row stores
        f16* dst = (which == 0) ? Qh : Kh;
        __syncthreads();
        #pragma unroll
        for (int j = 0; j < 4; j++) {
            int col = 64 * wc + 16 * j + lm;
            float bb = bias[n0 + col];
            #pragma unroll
            for (int i = 0; i < 4; i++) {
                int row = 64 * wr + 16 * i + 4 * qd;
                #pragma unroll
                for (int r = 0; r < 4; ++r)
                    smem[(row + r) * 136 + col] = (f16)(acc[i][j][r] + bb);
            }
        }
        __syncthreads();
        #pragma unroll
        for (int t = 0; t < 8; ++t) {
            int ci = tid + t * 256;            // 0..2047
            int row = ci >> 4, cg = ci & 15;
            f16x8 v = *(const f16x8*)&smem[row * 136 + cg * 8];
            int m = m0 + row;
            int b = m >> 11, s = m & 2047;
            int h = (n0 >> 6) + (cg >> 3);
            int d0 = (cg & 7) * 8;
            *(f16x8*)&dst[(((long)(b * 16 + h)) * 2048 + s) * 64 + d0] = v;
        }
    }
}

// ---------------- kernel 2: flash attention, split-K x2 --------------------
// grid 1024: (half, b, h, qt). Each block: 8 k-tiles of 128.
// Fixed-max softmax (M=4): partials additive -> fp32 O-numerator + per-head l.
__global__ __launch_bounds__(512, 8) void k_attn(
    const f16* __restrict__ Qh, const f16* __restrict__ Kh, const f16* __restrict__ Vt,
    const u64* __restrict__ mbits, float* __restrict__ On, float* __restrict__ lsum)
{
    int bid = blockIdx.x;
    int qt = bid & 15;
    int h = (bid >> 4) & 15;
    int b = (bid >> 8) & 1;
    int half = bid >> 9;
    int q0 = qt * 128;

    const f16* Qg = Qh + ((long)(b * 16 + h)) * 2048 * 64;
    const f16* Kg = Kh + ((long)(b * 16 + h)) * 2048 * 64;
    const f16* Vg = Vt + ((long)(b * 16 + h)) * 64 * 2048;

    __shared__ f16 ks[128 * 64];       // 16 KB  K tile [key][d]
    __shared__ f16 vs[64 * 128];       // 16 KB  V^T tile [d][key]
    __shared__ f16 ps[8][16 * 32];     //  8 KB  per-wave P [q16][key32]

    int tid = threadIdx.x, lane = tid & 63, wid = tid >> 6;
    int lm = lane & 15, qd = lane >> 4;

    int qrow = q0 + 16 * wid + lm;
    const u64* Mrow = mbits + ((long)(b * 2048) + qrow) * 32;

    f16x8 aq[2];
    #pragma unroll
    for (int ksi = 0; ksi < 2; ++ksi)
        aq[ksi] = *(const f16x8*)&Qg[(long)qrow * 64 + ksi * 32 + qd * 8];

    f32x4 oacc[4], lacc;
    #pragma unroll
    for (int c = 0; c < 4; c++) oacc[c] = (f32x4)0.0f;
    lacc = (f32x4)0.0f;
    f16x8 vone;
    #pragma unroll
    for (int j = 0; j < 8; j++) vone[j] = (f16)1.0f;

    // p = exp2(qk*c1 - |dist|*c2 - c3);  M = 4 fixed softmax max
    const float c1 = 0.0450842252f;                                   // (1/32)*log2e
    float negc2 = -__builtin_amdgcn_exp2f(-0.5f * (float)(h + 1)) * c1;
    const float c3 = 5.7707801634f;                                   // 4*log2e

    int kt0 = half * 8;
    for (int kk = 0; kk < 8; ++kk) {
        int kt = kt0 + kk;
        int k0 = kt * 128;
        __syncthreads();
        #pragma unroll
        for (int t = 0; t < 2; ++t) {
            int cid = tid + t * 512;          // 0..1023 16B chunks
            int row = cid >> 3, cg = cid & 7;
            int sw = cg ^ (row & 7);
            *(f16x8*)&ks[row * 64 + sw * 8] =
                *(const f16x8*)&Kg[(long)(k0 + row) * 64 + cg * 8];
            int vrow = cid >> 4, vg = cid & 15;
            int vsw = vg ^ (vrow & 7);
            *(f16x8*)&vs[vrow * 128 + vsw * 8] =
                *(const f16x8*)&Vg[(long)vrow * 2048 + k0 + vg * 8];
        }
        __syncthreads();

        u64 w0 = Mrow[kt * 2], w1 = Mrow[kt * 2 + 1];
        float qmk = (float)(qrow - k0);

        #pragma unroll
        for (int t = 0; t < 4; ++t) {
            // ---- QK for key chunk [32t, 32t+32) ----
            f32x4 sacc0 = (f32x4)0.0f, sacc1 = (f32x4)0.0f;
            #pragma unroll
            for (int ksi = 0; ksi < 2; ++ksi) {
                int kr0 = 32 * t + lm;
                int g0 = (ksi * 4 + qd) ^ (kr0 & 7);
                f16x8 ak0 = *(const f16x8*)&ks[kr0 * 64 + g0 * 8];
                sacc0 = MFMA16(ak0, aq[ksi], sacc0, 0, 0, 0);
                int kr1 = 32 * t + 16 + lm;
                int g1 = (ksi * 4 + qd) ^ (kr1 & 7);
                f16x8 ak1 = *(const f16x8*)&ks[kr1 * 64 + g1 * 8];
                sacc1 = MFMA16(ak1, aq[ksi], sacc1, 0, 0, 0);
            }
            // ---- softmax for the 2 16-key groups ----
            #pragma unroll
            for (int cc = 0; cc < 2; ++cc) {
                const f32x4& sa = cc ? sacc1 : sacc0;
                int c = 2 * t + cc;
                u32 nib = (u32)(((c < 4) ? w0 : w1) >> (16 * (c & 3) + 4 * qd)) & 15u;
                float qmkc = qmk - (float)(16 * c + 4 * qd);
                f16x4 pk;
                #pragma unroll
                for (int r = 0; r < 4; ++r) {
                    float t2 = fmaf(sa[r], c1, -c3);
                    float u = fmaf(fabsf(qmkc - (float)r), negc2, t2);
                    u = ((nib >> r) & 1u) ? u : -1e30f;
                    pk[r] = (f16)__builtin_amdgcn_exp2f(u);
                }
                *(f16x4*)&ps[wid][lm * 32 + cc * 16 + 4 * qd] = pk;
            }
            // ---- PV for this 32-key chunk (same-wave LDS round trip) ----
            f16x8 pa = *(const f16x8*)&ps[wid][lm * 32 + qd * 8];
            #pragma unroll
            for (int cc2 = 0; cc2 < 4; ++cc2) {
                int d = 16 * cc2 + lm;
                int g = (t * 4 + qd) ^ (d & 7);
                f16x8 vb = *(const f16x8*)&vs[d * 128 + g * 8];
                oacc[cc2] = MFMA16(pa, vb, oacc[cc2], 0, 0, 0);
            }
            lacc = MFMA16(pa, vone, lacc, 0, 0, 0);
        }
    }

    // ---- store fp32 partials; lsum is per (row, head) ----
    float* Onh = On + (long)half * 4096 * 1024;
    float* lh = lsum + half * 65536;           // [4096][16]
    int qloc = 16 * wid + 4 * qd;
    #pragma unroll
    for (int r = 0; r < 4; ++r) {
        long base = ((long)(b * 2048 + q0 + qloc + r)) * 1024 + h * 64;
        #pragma unroll
        for (int cc = 0; cc < 4; ++cc)
            Onh[base + 16 * cc + lm] = oacc[cc][r];
    }
    if (lm == 0) {
        #pragma unroll
        for (int r = 0; r < 4; ++r)
            lh[(b * 2048 + q0 + qloc + r) * 16 + h] = lacc[r];
    }
}

// ---------------- kernel 3: combine + output projection --------------------
// out[4096][1024] fp32 = ((On0+On1)/l[row][head]) * Wo^T + bo.
// K-tile kt spans exactly head kt's 64 columns -> per-head lv in staging.
__global__ __launch_bounds__(256) void k_proj(
    const float* __restrict__ On, const float* __restrict__ lsum,
    const float* __restrict__ wo, const float* __restrict__ bo,
    float* __restrict__ out)
{
    int bid = blockIdx.x;
    int tm = bid >> 3, tn = bid & 7;

    __shared__ f16 la[128 * 64];
    __shared__ f16 lb[128 * 64];

    int tid = threadIdx.x;
    int lane = tid & 63, wid = tid >> 6;
    int wr = wid >> 1, wc = wid & 1;
    int lm = lane & 15, qd = lane >> 4;

    f32x4 acc[4][4];
    #pragma unroll
    for (int i = 0; i < 4; i++)
        #pragma unroll
        for (int j = 0; j < 4; j++) acc[i][j] = (f32x4)0.0f;

    int m0 = tm * 128, n0 = tn * 128;

    for (int kt = 0; kt < 16; ++kt) {
        int k0 = kt * 64;
        __syncthreads();
        #pragma unroll
        for (int t = 0; t < 4; ++t) {
            int cid = tid + t * 256;
            int row = cid >> 3;
            int cg = cid & 7;
            int sw = cg ^ (row & 7);
            {
                int rg = m0 + row;
                float l0 = lsum[rg * 16 + kt];
                float l1 = lsum[65536 + rg * 16 + kt];
                float lv = 1.0f / fmaxf(l0 + l1, 1e-30f);
                const float4* p0 = (const float4*)&On[(long)rg * 1024 + k0 + cg * 8];
                const float4* p1 = (const float4*)((const char*)p0 + 16777216); // + 4096*1024 floats
                float4 a0 = p0[0], a1 = p0[1], b0 = p1[0], b1 = p1[1];
                f16x8 o;
                o[0]=(f16)((a0.x+b0.x)*lv); o[1]=(f16)((a0.y+b0.y)*lv);
                o[2]=(f16)((a0.z+b0.z)*lv); o[3]=(f16)((a0.w+b0.w)*lv);
                o[4]=(f16)((a1.x+b1.x)*lv); o[5]=(f16)((a1.y+b1.y)*lv);
                o[6]=(f16)((a1.z+b1.z)*lv); o[7]=(f16)((a1.w+b1.w)*lv);
                *(f16x8*)&la[row * 64 + sw * 8] = o;
            }
            {
                const float4* s4 = (const float4*)&wo[(long)(n0 + row) * 1024 + k0 + cg * 8];
                float4 a = s4[0], b2 = s4[1];
                f16x8 o;
                o[0]=(f16)a.x; o[1]=(f16)a.y; o[2]=(f16)a.z; o[3]=(f16)a.w;
                o[4]=(f16)b2.x; o[5]=(f16)b2.y; o[6]=(f16)b2.z; o[7]=(f16)b2.w;
                *(f16x8*)&lb[row * 64 + sw * 8] = o;
            }
        }
        __syncthreads();
        #pragma unroll
        for (int ks = 0; ks < 2; ++ks) {
            f16x8 af[4], bfr[4];
            #pragma unroll
            for (int i = 0; i < 4; i++) {
                int m = 64 * wr + 16 * i + lm;
                int g = (ks * 4 + qd) ^ (m & 7);
                af[i] = *(const f16x8*)&la[m * 64 + g * 8];
                int n = 64 * wc + 16 * i + lm;
                int g2 = (ks * 4 + qd) ^ (n & 7);
                bfr[i] = *(const f16x8*)&lb[n * 64 + g2 * 8];
            }
            #pragma unroll
            for (int i = 0; i < 4; i++)
                #pragma unroll
                for (int j = 0; j < 4; j++)
                    acc[i][j] = MFMA16(af[i], bfr[j], acc[i][j], 0, 0, 0);
        }
    }

    #pragma unroll
    for (int j = 0; j < 4; j++) {
        int n = n0 + 64 * wc + 16 * j + lm;
        float bb = bo[n];
        #pragma unroll
        for (int i = 0; i < 4; i++) {
            int mbase = m0 + 64 * wr + 16 * i + 4 * qd;
            #pragma unroll
            for (int r = 0; r < 4; ++r)
                out[(long)(mbase + r) * 1024 + n] = acc[i][j][r] + bb;
        }
    }
}

// ---------------- launch ----------------------------------------------------
extern "C" void kernel_launch(void* const* d_in, const int* in_sizes, int n_in,
                              void* d_out, int out_size, void* d_ws, size_t ws_size,
                              hipStream_t stream)
{
    const float* embed = (const float*)d_in[0];
    const float* key   = (const float*)d_in[1];
    const int*   mask  = (const int*)d_in[2];
    const float* Wq = (const float*)d_in[3];
    const float* bq = (const float*)d_in[4];
    const float* Wk = (const float*)d_in[5];
    const float* bk = (const float*)d_in[6];
    const float* Wv = (const float*)d_in[7];
    const float* bv = (const float*)d_in[8];
    const float* Wo = (const float*)d_in[9];
    const float* bo = (const float*)d_in[10];

    char* ws = (char*)d_ws;
    u64*   mb = (u64*)(ws + 0);            // 1 MB
    f16*   Qh = (f16*)(ws + 1048576);      // 8 MB  [B][H][S][64]
    f16*   Kh = (f16*)(ws + 9437184);      // 8 MB
    f16*   Vt = (f16*)(ws + 17825792);     // 8 MB  [B][H][64][S]
    float* On = (float*)(ws + 26214400);   // 32 MB [2][4096][1024] f32
    float* ls = (float*)(ws + 59768832);   // 512 KB [2][4096][16] f32
    float* out = (float*)d_out;

    k_qkvm<<<1792, 256, 0, stream>>>(embed, key, mask, Wq, Wk, Wv,
                                     bq, bk, bv, Qh, Kh, Vt, mb);
    k_attn<<<1024, 512, 0, stream>>>(Qh, Kh, Vt, mb, On, ls);
    k_proj<<<256, 256, 0, stream>>>(On, ls, Wo, bo, out);
}

// Round 6
// 343.261 us; speedup vs baseline: 1.1764x; 1.1764x over previous
//
#include <hip/hip_runtime.h>

// ---------------------------------------------------------------------------
// MultiheadAttention fwd, MI355X gfx950.
// B=2, S=2048, D=1024, H=16, DH=64.  fp16 compute, fp32 MFMA acc.
// R6: 4 dispatches. (1) convert fp32->fp16 + packmask merged (streaming).
// (2) QKV GEMM from compact fp16 (R3 structure, LDS-bounce epilogue).
// (3) attention split-K x2, fixed-max softmax, per-(row,head) lsum (R5 fix).
// (4) proj with fused combine: LDS-cached linv, fp16 Wo staging.
// Workspace: On aliases dead xe/xk/wq/wk/wv region (62.4 MB total).
// ---------------------------------------------------------------------------

typedef _Float16 f16;
typedef __attribute__((ext_vector_type(8))) _Float16 f16x8;
typedef __attribute__((ext_vector_type(4))) _Float16 f16x4;
typedef __attribute__((ext_vector_type(4))) float f32x4;
typedef unsigned long long u64;
typedef unsigned int u32;

#define MFMA16 __builtin_amdgcn_mfma_f32_16x16x32_f16

// ---------------- kernel 1: fp32 -> fp16 convert + mask packing ------------
// blocks [0,6144): stream-convert embed, key, Wq, Wk, Wv, Wo.
// blocks [6144,7168): pack attn_mask [2][2048][2048] i32 -> bits [4096][32] u64
__global__ __launch_bounds__(256) void k_convert(
    const float* __restrict__ embed, const float* __restrict__ key,
    const float* __restrict__ wq, const float* __restrict__ wk,
    const float* __restrict__ wv, const float* __restrict__ wo,
    const int* __restrict__ mask,
    f16* __restrict__ xe, f16* __restrict__ xk,
    f16* __restrict__ wqh, f16* __restrict__ wkh,
    f16* __restrict__ wvh, f16* __restrict__ woh,
    u64* __restrict__ bits)
{
    int bid = blockIdx.x;
    if (bid >= 6144) {
        int gw = (bid - 6144) * 4 + (threadIdx.x >> 6);   // row 0..4095
        int lane = threadIdx.x & 63;
        const int* row = mask + (long)gw * 2048;
        u64* outb = bits + (long)gw * 32;
        #pragma unroll 4
        for (int c = 0; c < 32; ++c) {
            int v = row[c * 64 + lane];
            u64 bm = __ballot(v != 0);
            if (lane == 0) outb[c] = bm;
        }
        return;
    }
    long g = (long)bid * 256 + threadIdx.x;   // one 8-float group
    const float* src; f16* dst; long off;
    if (g < 524288)       { src = embed; dst = xe; off = g; }
    else if (g < 1048576) { src = key;   dst = xk; off = g - 524288; }
    else {
        long t = g - 1048576; int wi = (int)(t >> 17); off = t & 131071;
        if (wi == 0)      { src = wq; dst = wqh; }
        else if (wi == 1) { src = wk; dst = wkh; }
        else if (wi == 2) { src = wv; dst = wvh; }
        else              { src = wo; dst = woh; }
    }
    const float4* s4 = (const float4*)src;
    float4 a = s4[off * 2], b = s4[off * 2 + 1];
    f16x8 o;
    o[0]=(f16)a.x; o[1]=(f16)a.y; o[2]=(f16)a.z; o[3]=(f16)a.w;
    o[4]=(f16)b.x; o[5]=(f16)b.y; o[6]=(f16)b.z; o[7]=(f16)b.w;
    *(f16x8*)(dst + off * 8) = o;
}

// ---------------- kernel 2: fused QKV GEMM (fp16 in) -----------------------
// C[4096][1024] = X W^T + bias; which 0:Q / 1:K -> [B][H][S][64] via LDS
// bounce; 2: V -> [B][H][64][S] direct b64.
__global__ __launch_bounds__(256) void k_qkv(
    const f16* __restrict__ xe, const f16* __restrict__ xk,
    const f16* __restrict__ wqh, const f16* __restrict__ wkh, const f16* __restrict__ wvh,
    const float* __restrict__ bq, const float* __restrict__ bk, const float* __restrict__ bv,
    f16* __restrict__ Qh, f16* __restrict__ Kh, f16* __restrict__ Vt)
{
    int bid = blockIdx.x;
    int which = bid >> 8;
    int rr_ = bid & 255;
    int tm = rr_ >> 3, tn = rr_ & 7;
    const f16* X = (which == 0) ? xe : xk;
    const f16* W = (which == 0) ? wqh : (which == 1) ? wkh : wvh;
    const float* bias = (which == 0) ? bq : (which == 1) ? bk : bv;

    __shared__ f16 smem[128 * 136];
    f16* la = smem;
    f16* lb = smem + 128 * 64;

    int tid = threadIdx.x;
    int lane = tid & 63, wid = tid >> 6;
    int wr = wid >> 1, wc = wid & 1;
    int lm = lane & 15, qd = lane >> 4;

    f32x4 acc[4][4];
    #pragma unroll
    for (int i = 0; i < 4; i++)
        #pragma unroll
        for (int j = 0; j < 4; j++) acc[i][j] = (f32x4)0.0f;

    int m0 = tm * 128, n0 = tn * 128;

    for (int kt = 0; kt < 16; ++kt) {
        int k0 = kt * 64;
        __syncthreads();
        #pragma unroll
        for (int t = 0; t < 4; ++t) {
            int cid = tid + t * 256;          // 0..1023 16B chunks
            int row = cid >> 3;
            int cg = cid & 7;
            int sw = cg ^ (row & 7);
            *(f16x8*)&la[row * 64 + sw * 8] =
                *(const f16x8*)&X[(long)(m0 + row) * 1024 + k0 + cg * 8];
            *(f16x8*)&lb[row * 64 + sw * 8] =
                *(const f16x8*)&W[(long)(n0 + row) * 1024 + k0 + cg * 8];
        }
        __syncthreads();
        #pragma unroll
        for (int ks = 0; ks < 2; ++ks) {
            f16x8 af[4], bfr[4];
            #pragma unroll
            for (int i = 0; i < 4; i++) {
                int m = 64 * wr + 16 * i + lm;
                int g = (ks * 4 + qd) ^ (m & 7);
                af[i] = *(const f16x8*)&la[m * 64 + g * 8];
                int n = 64 * wc + 16 * i + lm;
                int g2 = (ks * 4 + qd) ^ (n & 7);
                bfr[i] = *(const f16x8*)&lb[n * 64 + g2 * 8];
            }
            #pragma unroll
            for (int i = 0; i < 4; i++)
                #pragma unroll
                for (int j = 0; j < 4; j++)
                    acc[i][j] = MFMA16(af[i], bfr[j], acc[i][j], 0, 0, 0);
        }
    }

    if (which == 2) {
        // V: direct transposed store [B][H][64][S], b64 along s
        #pragma unroll
        for (int j = 0; j < 4; j++) {
            int n = n0 + 64 * wc + 16 * j + lm;
            float bb = bias[n];
            int h = n >> 6, d = n & 63;
            #pragma unroll
            for (int i = 0; i < 4; i++) {
                int mbase = m0 + 64 * wr + 16 * i + 4 * qd;
                f16x4 pk;
                #pragma unroll
                for (int r = 0; r < 4; ++r) pk[r] = (f16)(acc[i][j][r] + bb);
                int b = mbase >> 11, s = mbase & 2047;
                *(f16x4*)&Vt[(((long)(b * 16 + h)) * 64 + d) * 2048 + s] = pk;
            }
        }
    } else {
        // Q/K: LDS bounce -> coalesced b128 row stores
        f16* dst = (which == 0) ? Qh : Kh;
        __syncthreads();
        #pragma unroll
        for (int j = 0; j < 4; j++) {
            int col = 64 * wc + 16 * j + lm;
            float bb = bias[n0 + col];
            #pragma unroll
            for (int i = 0; i < 4; i++) {
                int row = 64 * wr + 16 * i + 4 * qd;
                #pragma unroll
                for (int r = 0; r < 4; ++r)
                    smem[(row + r) * 136 + col] = (f16)(acc[i][j][r] + bb);
            }
        }
        __syncthreads();
        #pragma unroll
        for (int t = 0; t < 8; ++t) {
            int ci = tid + t * 256;            // 0..2047
            int row = ci >> 4, cg = ci & 15;
            f16x8 v = *(const f16x8*)&smem[row * 136 + cg * 8];
            int m = m0 + row;
            int b = m >> 11, s = m & 2047;
            int h = (n0 >> 6) + (cg >> 3);
            int d0 = (cg & 7) * 8;
            *(f16x8*)&dst[(((long)(b * 16 + h)) * 2048 + s) * 64 + d0] = v;
        }
    }
}

// ---------------- kernel 3: flash attention, split-K x2 --------------------
// grid 1024: (half, b, h, qt). Each block: 8 k-tiles of 128.
// Fixed-max softmax (M=4): partials additive -> fp32 O-numerator + per-head l.
__global__ __launch_bounds__(512, 8) void k_attn(
    const f16* __restrict__ Qh, const f16* __restrict__ Kh, const f16* __restrict__ Vt,
    const u64* __restrict__ mbits, float* __restrict__ On, float* __restrict__ lsum)
{
    int bid = blockIdx.x;
    int qt = bid & 15;
    int h = (bid >> 4) & 15;
    int b = (bid >> 8) & 1;
    int half = bid >> 9;
    int q0 = qt * 128;

    const f16* Qg = Qh + ((long)(b * 16 + h)) * 2048 * 64;
    const f16* Kg = Kh + ((long)(b * 16 + h)) * 2048 * 64;
    const f16* Vg = Vt + ((long)(b * 16 + h)) * 64 * 2048;

    __shared__ f16 ks[128 * 64];       // 16 KB  K tile [key][d]
    __shared__ f16 vs[64 * 128];       // 16 KB  V^T tile [d][key]
    __shared__ f16 ps[8][16 * 32];     //  8 KB  per-wave P [q16][key32]

    int tid = threadIdx.x, lane = tid & 63, wid = tid >> 6;
    int lm = lane & 15, qd = lane >> 4;

    int qrow = q0 + 16 * wid + lm;
    const u64* Mrow = mbits + ((long)(b * 2048) + qrow) * 32;

    f16x8 aq[2];
    #pragma unroll
    for (int ksi = 0; ksi < 2; ++ksi)
        aq[ksi] = *(const f16x8*)&Qg[(long)qrow * 64 + ksi * 32 + qd * 8];

    f32x4 oacc[4], lacc;
    #pragma unroll
    for (int c = 0; c < 4; c++) oacc[c] = (f32x4)0.0f;
    lacc = (f32x4)0.0f;
    f16x8 vone;
    #pragma unroll
    for (int j = 0; j < 8; j++) vone[j] = (f16)1.0f;

    // p = exp2(qk*c1 - |dist|*c2 - c3);  M = 4 fixed softmax max
    const float c1 = 0.0450842252f;                                   // (1/32)*log2e
    float negc2 = -__builtin_amdgcn_exp2f(-0.5f * (float)(h + 1)) * c1;
    const float c3 = 5.7707801634f;                                   // 4*log2e

    int kt0 = half * 8;
    for (int kk = 0; kk < 8; ++kk) {
        int kt = kt0 + kk;
        int k0 = kt * 128;
        __syncthreads();
        #pragma unroll
        for (int t = 0; t < 2; ++t) {
            int cid = tid + t * 512;          // 0..1023 16B chunks
            int row = cid >> 3, cg = cid & 7;
            int sw = cg ^ (row & 7);
            *(f16x8*)&ks[row * 64 + sw * 8] =
                *(const f16x8*)&Kg[(long)(k0 + row) * 64 + cg * 8];
            int vrow = cid >> 4, vg = cid & 15;
            int vsw = vg ^ (vrow & 7);
            *(f16x8*)&vs[vrow * 128 + vsw * 8] =
                *(const f16x8*)&Vg[(long)vrow * 2048 + k0 + vg * 8];
        }
        __syncthreads();

        u64 w0 = Mrow[kt * 2], w1 = Mrow[kt * 2 + 1];
        float qmk = (float)(qrow - k0);

        #pragma unroll
        for (int t = 0; t < 4; ++t) {
            // ---- QK for key chunk [32t, 32t+32) ----
            f32x4 sacc0 = (f32x4)0.0f, sacc1 = (f32x4)0.0f;
            #pragma unroll
            for (int ksi = 0; ksi < 2; ++ksi) {
                int kr0 = 32 * t + lm;
                int g0 = (ksi * 4 + qd) ^ (kr0 & 7);
                f16x8 ak0 = *(const f16x8*)&ks[kr0 * 64 + g0 * 8];
                sacc0 = MFMA16(ak0, aq[ksi], sacc0, 0, 0, 0);
                int kr1 = 32 * t + 16 + lm;
                int g1 = (ksi * 4 + qd) ^ (kr1 & 7);
                f16x8 ak1 = *(const f16x8*)&ks[kr1 * 64 + g1 * 8];
                sacc1 = MFMA16(ak1, aq[ksi], sacc1, 0, 0, 0);
            }
            // ---- softmax for the 2 16-key groups ----
            #pragma unroll
            for (int cc = 0; cc < 2; ++cc) {
                const f32x4& sa = cc ? sacc1 : sacc0;
                int c = 2 * t + cc;
                u32 nib = (u32)(((c < 4) ? w0 : w1) >> (16 * (c & 3) + 4 * qd)) & 15u;
                float qmkc = qmk - (float)(16 * c + 4 * qd);
                f16x4 pk;
                #pragma unroll
                for (int r = 0; r < 4; ++r) {
                    float t2 = fmaf(sa[r], c1, -c3);
                    float u = fmaf(fabsf(qmkc - (float)r), negc2, t2);
                    u = ((nib >> r) & 1u) ? u : -1e30f;
                    pk[r] = (f16)__builtin_amdgcn_exp2f(u);
                }
                *(f16x4*)&ps[wid][lm * 32 + cc * 16 + 4 * qd] = pk;
            }
            // ---- PV for this 32-key chunk (same-wave LDS round trip) ----
            f16x8 pa = *(const f16x8*)&ps[wid][lm * 32 + qd * 8];
            #pragma unroll
            for (int cc2 = 0; cc2 < 4; ++cc2) {
                int d = 16 * cc2 + lm;
                int g = (t * 4 + qd) ^ (d & 7);
                f16x8 vb = *(const f16x8*)&vs[d * 128 + g * 8];
                oacc[cc2] = MFMA16(pa, vb, oacc[cc2], 0, 0, 0);
            }
            lacc = MFMA16(pa, vone, lacc, 0, 0, 0);
        }
    }

    // ---- store fp32 partials; lsum is per (row, head) ----
    float* Onh = On + (long)half * 4096 * 1024;
    float* lh = lsum + half * 65536;           // [4096][16]
    int qloc = 16 * wid + 4 * qd;
    #pragma unroll
    for (int r = 0; r < 4; ++r) {
        long base = ((long)(b * 2048 + q0 + qloc + r)) * 1024 + h * 64;
        #pragma unroll
        for (int cc = 0; cc < 4; ++cc)
            Onh[base + 16 * cc + lm] = oacc[cc][r];
    }
    if (lm == 0) {
        #pragma unroll
        for (int r = 0; r < 4; ++r)
            lh[(b * 2048 + q0 + qloc + r) * 16 + h] = lacc[r];
    }
}

// ---------------- kernel 4: combine + output projection --------------------
// out[4096][1024] fp32 = ((On0+On1) * linv[row][head]) * Wo^T + bo.
// K-tile kt spans exactly head kt's columns; linv cached in LDS per block.
__global__ __launch_bounds__(256) void k_proj(
    const float* __restrict__ On, const float* __restrict__ lsum,
    const f16* __restrict__ woh, const float* __restrict__ bo,
    float* __restrict__ out)
{
    int bid = blockIdx.x;
    int tm = bid >> 3, tn = bid & 7;

    __shared__ f16 la[128 * 64];
    __shared__ f16 lb[128 * 64];
    __shared__ float linv_s[128 * 16];   // 8 KB, [row][head]

    int tid = threadIdx.x;
    int lane = tid & 63, wid = tid >> 6;
    int wr = wid >> 1, wc = wid & 1;
    int lm = lane & 15, qd = lane >> 4;

    int m0 = tm * 128, n0 = tn * 128;

    // build linv once (coalesced float4 loads of lsum[m0..m0+128)[0..16))
    #pragma unroll
    for (int t = 0; t < 2; ++t) {
        int i4 = tid * 2 + t;             // 0..511 float4s
        float4 a = *(const float4*)&lsum[m0 * 16 + i4 * 4];
        float4 b = *(const float4*)&lsum[65536 + m0 * 16 + i4 * 4];
        float4 r;
        r.x = 1.0f / fmaxf(a.x + b.x, 1e-30f);
        r.y = 1.0f / fmaxf(a.y + b.y, 1e-30f);
        r.z = 1.0f / fmaxf(a.z + b.z, 1e-30f);
        r.w = 1.0f / fmaxf(a.w + b.w, 1e-30f);
        *(float4*)&linv_s[i4 * 4] = r;
    }

    f32x4 acc[4][4];
    #pragma unroll
    for (int i = 0; i < 4; i++)
        #pragma unroll
        for (int j = 0; j < 4; j++) acc[i][j] = (f32x4)0.0f;

    for (int kt = 0; kt < 16; ++kt) {
        int k0 = kt * 64;
        __syncthreads();
        #pragma unroll
        for (int t = 0; t < 4; ++t) {
            int cid = tid + t * 256;
            int row = cid >> 3;
            int cg = cid & 7;
            int sw = cg ^ (row & 7);
            {
                int rg = m0 + row;
                float lv = linv_s[row * 16 + kt];
                const float4* p0 = (const float4*)&On[(long)rg * 1024 + k0 + cg * 8];
                const float4* p1 = (const float4*)((const char*)p0 + 16777216);
                float4 a0 = p0[0], a1 = p0[1], b0 = p1[0], b1 = p1[1];
                f16x8 o;
                o[0]=(f16)((a0.x+b0.x)*lv); o[1]=(f16)((a0.y+b0.y)*lv);
                o[2]=(f16)((a0.z+b0.z)*lv); o[3]=(f16)((a0.w+b0.w)*lv);
                o[4]=(f16)((a1.x+b1.x)*lv); o[5]=(f16)((a1.y+b1.y)*lv);
                o[6]=(f16)((a1.z+b1.z)*lv); o[7]=(f16)((a1.w+b1.w)*lv);
                *(f16x8*)&la[row * 64 + sw * 8] = o;
            }
            *(f16x8*)&lb[row * 64 + sw * 8] =
                *(const f16x8*)&woh[(long)(n0 + row) * 1024 + k0 + cg * 8];
        }
        __syncthreads();
        #pragma unroll
        for (int ks = 0; ks < 2; ++ks) {
            f16x8 af[4], bfr[4];
            #pragma unroll
            for (int i = 0; i < 4; i++) {
                int m = 64 * wr + 16 * i + lm;
                int g = (ks * 4 + qd) ^ (m & 7);
                af[i] = *(const f16x8*)&la[m * 64 + g * 8];
                int n = 64 * wc + 16 * i + lm;
                int g2 = (ks * 4 + qd) ^ (n & 7);
                bfr[i] = *(const f16x8*)&lb[n * 64 + g2 * 8];
            }
            #pragma unroll
            for (int i = 0; i < 4; i++)
                #pragma unroll
                for (int j = 0; j < 4; j++)
                    acc[i][j] = MFMA16(af[i], bfr[j], acc[i][j], 0, 0, 0);
        }
    }

    #pragma unroll
    for (int j = 0; j < 4; j++) {
        int n = n0 + 64 * wc + 16 * j + lm;
        float bb = bo[n];
        #pragma unroll
        for (int i = 0; i < 4; i++) {
            int mbase = m0 + 64 * wr + 16 * i + 4 * qd;
            #pragma unroll
            for (int r = 0; r < 4; ++r)
                out[(long)(mbase + r) * 1024 + n] = acc[i][j][r] + bb;
        }
    }
}

// ---------------- launch ----------------------------------------------------
extern "C" void kernel_launch(void* const* d_in, const int* in_sizes, int n_in,
                              void* d_out, int out_size, void* d_ws, size_t ws_size,
                              hipStream_t stream)
{
    const float* embed = (const float*)d_in[0];
    const float* key   = (const float*)d_in[1];
    const int*   mask  = (const int*)d_in[2];
    const float* Wq = (const float*)d_in[3];
    const float* bq = (const float*)d_in[4];
    const float* Wk = (const float*)d_in[5];
    const float* bk = (const float*)d_in[6];
    const float* Wv = (const float*)d_in[7];
    const float* bv = (const float*)d_in[8];
    const float* Wo = (const float*)d_in[9];
    const float* bo = (const float*)d_in[10];

    char* ws = (char*)d_ws;
    u64*   mb  = (u64*)(ws + 0);            // 1 MB
    // --- region [1M, 34.6M): xe/xk/wqh/wkh/wvh, dead after k_qkv; On aliases it
    f16*   xe  = (f16*)(ws + 1048576);      // 8 MB
    f16*   xk  = (f16*)(ws + 9437184);      // 8 MB
    f16*   wqh = (f16*)(ws + 17825792);     // 2 MB
    f16*   wkh = (f16*)(ws + 19922944);     // 2 MB
    f16*   wvh = (f16*)(ws + 22020096);     // 2 MB
    float* On  = (float*)(ws + 1048576);    // 32 MB [2][4096][1024] (aliases above)
    // --- persistent region
    f16*   woh = (f16*)(ws + 34603008);     // 2 MB
    f16*   Qh  = (f16*)(ws + 36700160);     // 8 MB  [B][H][S][64]
    f16*   Kh  = (f16*)(ws + 45088768);     // 8 MB
    f16*   Vt  = (f16*)(ws + 53477376);     // 8 MB  [B][H][64][S]
    float* ls  = (float*)(ws + 61865984);   // 512 KB [2][4096][16]
    float* out = (float*)d_out;

    k_convert<<<7168, 256, 0, stream>>>(embed, key, Wq, Wk, Wv, Wo, mask,
                                        xe, xk, wqh, wkh, wvh, woh, mb);
    k_qkv<<<768, 256, 0, stream>>>(xe, xk, wqh, wkh, wvh, bq, bk, bv, Qh, Kh, Vt);
    k_attn<<<1024, 512, 0, stream>>>(Qh, Kh, Vt, mb, On, ls);
    k_proj<<<256, 256, 0, stream>>>(On, ls, Wo == nullptr ? nullptr : woh, bo, out);
}

// Round 7
// 296.034 us; speedup vs baseline: 1.3640x; 1.1595x over previous
//
#include <hip/hip_runtime.h>

// ---------------------------------------------------------------------------
// MultiheadAttention fwd, MI355X gfx950.
// B=2, S=2048, D=1024, H=16, DH=64.  fp16 compute, fp32 MFMA acc.
// R7: 4 dispatches. (1) convert fp32->fp16 + packmask. (2) QKV GEMM fp16.
// (3) single-pass attention, interleaved QK/softmax/PV per 32-key chunk,
//     q-tile 64, 256 thr, 36KB LDS -> 4 blocks/CU, XCD-swizzled (b,h) L2
//     locality, direct f16 output. (4) proj fp16.
// ---------------------------------------------------------------------------

typedef _Float16 f16;
typedef __attribute__((ext_vector_type(8))) _Float16 f16x8;
typedef __attribute__((ext_vector_type(4))) _Float16 f16x4;
typedef __attribute__((ext_vector_type(4))) float f32x4;
typedef unsigned long long u64;
typedef unsigned int u32;

#define MFMA16 __builtin_amdgcn_mfma_f32_16x16x32_f16

// ---------------- kernel 1: fp32 -> fp16 convert + mask packing ------------
__global__ __launch_bounds__(256) void k_convert(
    const float* __restrict__ embed, const float* __restrict__ key,
    const float* __restrict__ wq, const float* __restrict__ wk,
    const float* __restrict__ wv, const float* __restrict__ wo,
    const int* __restrict__ mask,
    f16* __restrict__ xe, f16* __restrict__ xk,
    f16* __restrict__ wqh, f16* __restrict__ wkh,
    f16* __restrict__ wvh, f16* __restrict__ woh,
    u64* __restrict__ bits)
{
    int bid = blockIdx.x;
    if (bid >= 6144) {
        int gw = (bid - 6144) * 4 + (threadIdx.x >> 6);   // row 0..4095
        int lane = threadIdx.x & 63;
        const int* row = mask + (long)gw * 2048;
        u64* outb = bits + (long)gw * 32;
        #pragma unroll 4
        for (int c = 0; c < 32; ++c) {
            int v = row[c * 64 + lane];
            u64 bm = __ballot(v != 0);
            if (lane == 0) outb[c] = bm;
        }
        return;
    }
    long g = (long)bid * 256 + threadIdx.x;   // one 8-float group
    const float* src; f16* dst; long off;
    if (g < 524288)       { src = embed; dst = xe; off = g; }
    else if (g < 1048576) { src = key;   dst = xk; off = g - 524288; }
    else {
        long t = g - 1048576; int wi = (int)(t >> 17); off = t & 131071;
        if (wi == 0)      { src = wq; dst = wqh; }
        else if (wi == 1) { src = wk; dst = wkh; }
        else if (wi == 2) { src = wv; dst = wvh; }
        else              { src = wo; dst = woh; }
    }
    const float4* s4 = (const float4*)src;
    float4 a = s4[off * 2], b = s4[off * 2 + 1];
    f16x8 o;
    o[0]=(f16)a.x; o[1]=(f16)a.y; o[2]=(f16)a.z; o[3]=(f16)a.w;
    o[4]=(f16)b.x; o[5]=(f16)b.y; o[6]=(f16)b.z; o[7]=(f16)b.w;
    *(f16x8*)(dst + off * 8) = o;
}

// ---------------- kernel 2: fused QKV GEMM (fp16 in) -----------------------
__global__ __launch_bounds__(256) void k_qkv(
    const f16* __restrict__ xe, const f16* __restrict__ xk,
    const f16* __restrict__ wqh, const f16* __restrict__ wkh, const f16* __restrict__ wvh,
    const float* __restrict__ bq, const float* __restrict__ bk, const float* __restrict__ bv,
    f16* __restrict__ Qh, f16* __restrict__ Kh, f16* __restrict__ Vt)
{
    int bid = blockIdx.x;
    int which = bid >> 8;
    int rr_ = bid & 255;
    int tm = rr_ >> 3, tn = rr_ & 7;
    const f16* X = (which == 0) ? xe : xk;
    const f16* W = (which == 0) ? wqh : (which == 1) ? wkh : wvh;
    const float* bias = (which == 0) ? bq : (which == 1) ? bk : bv;

    __shared__ f16 smem[128 * 136];
    f16* la = smem;
    f16* lb = smem + 128 * 64;

    int tid = threadIdx.x;
    int lane = tid & 63, wid = tid >> 6;
    int wr = wid >> 1, wc = wid & 1;
    int lm = lane & 15, qd = lane >> 4;

    f32x4 acc[4][4];
    #pragma unroll
    for (int i = 0; i < 4; i++)
        #pragma unroll
        for (int j = 0; j < 4; j++) acc[i][j] = (f32x4)0.0f;

    int m0 = tm * 128, n0 = tn * 128;

    for (int kt = 0; kt < 16; ++kt) {
        int k0 = kt * 64;
        __syncthreads();
        #pragma unroll
        for (int t = 0; t < 4; ++t) {
            int cid = tid + t * 256;          // 0..1023 16B chunks
            int row = cid >> 3;
            int cg = cid & 7;
            int sw = cg ^ (row & 7);
            *(f16x8*)&la[row * 64 + sw * 8] =
                *(const f16x8*)&X[(long)(m0 + row) * 1024 + k0 + cg * 8];
            *(f16x8*)&lb[row * 64 + sw * 8] =
                *(const f16x8*)&W[(long)(n0 + row) * 1024 + k0 + cg * 8];
        }
        __syncthreads();
        #pragma unroll
        for (int ks = 0; ks < 2; ++ks) {
            f16x8 af[4], bfr[4];
            #pragma unroll
            for (int i = 0; i < 4; i++) {
                int m = 64 * wr + 16 * i + lm;
                int g = (ks * 4 + qd) ^ (m & 7);
                af[i] = *(const f16x8*)&la[m * 64 + g * 8];
                int n = 64 * wc + 16 * i + lm;
                int g2 = (ks * 4 + qd) ^ (n & 7);
                bfr[i] = *(const f16x8*)&lb[n * 64 + g2 * 8];
            }
            #pragma unroll
            for (int i = 0; i < 4; i++)
                #pragma unroll
                for (int j = 0; j < 4; j++)
                    acc[i][j] = MFMA16(af[i], bfr[j], acc[i][j], 0, 0, 0);
        }
    }

    if (which == 2) {
        // V: direct transposed store [B][H][64][S], b64 along s
        #pragma unroll
        for (int j = 0; j < 4; j++) {
            int n = n0 + 64 * wc + 16 * j + lm;
            float bb = bias[n];
            int h = n >> 6, d = n & 63;
            #pragma unroll
            for (int i = 0; i < 4; i++) {
                int mbase = m0 + 64 * wr + 16 * i + 4 * qd;
                f16x4 pk;
                #pragma unroll
                for (int r = 0; r < 4; ++r) pk[r] = (f16)(acc[i][j][r] + bb);
                int b = mbase >> 11, s = mbase & 2047;
                *(f16x4*)&Vt[(((long)(b * 16 + h)) * 64 + d) * 2048 + s] = pk;
            }
        }
    } else {
        // Q/K: LDS bounce -> coalesced b128 row stores
        f16* dst = (which == 0) ? Qh : Kh;
        __syncthreads();
        #pragma unroll
        for (int j = 0; j < 4; j++) {
            int col = 64 * wc + 16 * j + lm;
            float bb = bias[n0 + col];
            #pragma unroll
            for (int i = 0; i < 4; i++) {
                int row = 64 * wr + 16 * i + 4 * qd;
                #pragma unroll
                for (int r = 0; r < 4; ++r)
                    smem[(row + r) * 136 + col] = (f16)(acc[i][j][r] + bb);
            }
        }
        __syncthreads();
        #pragma unroll
        for (int t = 0; t < 8; ++t) {
            int ci = tid + t * 256;            // 0..2047
            int row = ci >> 4, cg = ci & 15;
            f16x8 v = *(const f16x8*)&smem[row * 136 + cg * 8];
            int m = m0 + row;
            int b = m >> 11, s = m & 2047;
            int h = (n0 >> 6) + (cg >> 3);
            int d0 = (cg & 7) * 8;
            *(f16x8*)&dst[(((long)(b * 16 + h)) * 2048 + s) * 64 + d0] = v;
        }
    }
}

// ---------------- kernel 3: flash attention, single pass -------------------
// grid 1024, 256 thr (4 waves x 16 q). q-tile 64. XCD swizzle: bid=(j<<3)|x,
// bh=(j>>5)*8+x, qt=j&31 -> all 32 q-blocks of one (b,h) on one XCD (K/V in L2).
// Fixed-max softmax (M=4); interleaved QK->softmax->PV per 32-key chunk.
__global__ __launch_bounds__(256, 4) void k_attn(
    const f16* __restrict__ Qh, const f16* __restrict__ Kh, const f16* __restrict__ Vt,
    const u64* __restrict__ mbits, f16* __restrict__ O)
{
    int bid = blockIdx.x;
    int x = bid & 7, j = bid >> 3;
    int bh = ((j >> 5) << 3) + x;        // 0..31
    int qt = j & 31;                     // 0..31
    int b = bh >> 4, h = bh & 15;
    int q0 = qt * 64;

    const f16* Qg = Qh + ((long)bh) * 2048 * 64;
    const f16* Kg = Kh + ((long)bh) * 2048 * 64;
    const f16* Vg = Vt + ((long)bh) * 64 * 2048;

    __shared__ f16 ks[128 * 64];       // 16 KB  K tile [key][d]
    __shared__ f16 vs[64 * 128];       // 16 KB  V^T tile [d][key]
    __shared__ f16 ps[4][16 * 32];     //  4 KB  per-wave P [q16][key32]

    int tid = threadIdx.x, lane = tid & 63, wid = tid >> 6;
    int lm = lane & 15, qd = lane >> 4;

    int qrow = q0 + 16 * wid + lm;
    const u64* Mrow = mbits + ((long)(b * 2048) + qrow) * 32;

    f16x8 aq[2];
    #pragma unroll
    for (int ksi = 0; ksi < 2; ++ksi)
        aq[ksi] = *(const f16x8*)&Qg[(long)qrow * 64 + ksi * 32 + qd * 8];

    f32x4 oacc[4], lacc;
    #pragma unroll
    for (int c = 0; c < 4; c++) oacc[c] = (f32x4)0.0f;
    lacc = (f32x4)0.0f;
    f16x8 vone;
    #pragma unroll
    for (int jj = 0; jj < 8; jj++) vone[jj] = (f16)1.0f;

    // p = exp2(qk*c1 - |dist|*c2 - c3);  M = 4 fixed softmax max
    const float c1 = 0.0450842252f;                                   // (1/32)*log2e
    float negc2 = -__builtin_amdgcn_exp2f(-0.5f * (float)(h + 1)) * c1;
    const float c3 = 5.7707801634f;                                   // 4*log2e

    for (int kt = 0; kt < 16; ++kt) {
        int k0 = kt * 128;
        __syncthreads();
        #pragma unroll
        for (int t = 0; t < 4; ++t) {
            int cid = tid + t * 256;          // 0..1023 16B chunks
            int row = cid >> 3, cg = cid & 7;
            int sw = cg ^ (row & 7);
            *(f16x8*)&ks[row * 64 + sw * 8] =
                *(const f16x8*)&Kg[(long)(k0 + row) * 64 + cg * 8];
            int vrow = cid >> 4, vg = cid & 15;
            int vsw = vg ^ (vrow & 7);
            *(f16x8*)&vs[vrow * 128 + vsw * 8] =
                *(const f16x8*)&Vg[(long)vrow * 2048 + k0 + vg * 8];
        }
        __syncthreads();

        u64 w0 = Mrow[kt * 2], w1 = Mrow[kt * 2 + 1];
        float qmk = (float)(qrow - k0);

        #pragma unroll
        for (int t = 0; t < 4; ++t) {
            // ---- QK for key chunk [32t, 32t+32) ----
            f32x4 sacc0 = (f32x4)0.0f, sacc1 = (f32x4)0.0f;
            #pragma unroll
            for (int ksi = 0; ksi < 2; ++ksi) {
                int kr0 = 32 * t + lm;
                int g0 = (ksi * 4 + qd) ^ (kr0 & 7);
                f16x8 ak0 = *(const f16x8*)&ks[kr0 * 64 + g0 * 8];
                sacc0 = MFMA16(ak0, aq[ksi], sacc0, 0, 0, 0);
                int kr1 = 32 * t + 16 + lm;
                int g1 = (ksi * 4 + qd) ^ (kr1 & 7);
                f16x8 ak1 = *(const f16x8*)&ks[kr1 * 64 + g1 * 8];
                sacc1 = MFMA16(ak1, aq[ksi], sacc1, 0, 0, 0);
            }
            // ---- softmax for the 2 16-key groups ----
            #pragma unroll
            for (int cc = 0; cc < 2; ++cc) {
                const f32x4& sa = cc ? sacc1 : sacc0;
                int c = 2 * t + cc;
                u32 nib = (u32)(((c < 4) ? w0 : w1) >> (16 * (c & 3) + 4 * qd)) & 15u;
                float qmkc = qmk - (float)(16 * c + 4 * qd);
                f16x4 pk;
                #pragma unroll
                for (int r = 0; r < 4; ++r) {
                    float t2 = fmaf(sa[r], c1, -c3);
                    float u = fmaf(fabsf(qmkc - (float)r), negc2, t2);
                    u = ((nib >> r) & 1u) ? u : -1e30f;
                    pk[r] = (f16)__builtin_amdgcn_exp2f(u);
                }
                *(f16x4*)&ps[wid][lm * 32 + cc * 16 + 4 * qd] = pk;
            }
            // ---- PV for this 32-key chunk (same-wave LDS round trip) ----
            f16x8 pa = *(const f16x8*)&ps[wid][lm * 32 + qd * 8];
            #pragma unroll
            for (int cc2 = 0; cc2 < 4; ++cc2) {
                int d = 16 * cc2 + lm;
                int g = (t * 4 + qd) ^ (d & 7);
                f16x8 vb = *(const f16x8*)&vs[d * 128 + g * 8];
                oacc[cc2] = MFMA16(pa, vb, oacc[cc2], 0, 0, 0);
            }
            lacc = MFMA16(pa, vone, lacc, 0, 0, 0);
        }
    }

    // epilogue: O[b][q][h*64+d] fp16
    #pragma unroll
    for (int r = 0; r < 4; ++r) {
        float linv = 1.0f / fmaxf(lacc[r], 1e-30f);
        long rowbase = ((long)(b * 2048 + q0 + 16 * wid + 4 * qd + r)) * 1024 + h * 64;
        #pragma unroll
        for (int cc = 0; cc < 4; ++cc)
            O[rowbase + 16 * cc + lm] = (f16)(oacc[cc][r] * linv);
    }
}

// ---------------- kernel 4: output projection ------------------------------
__global__ __launch_bounds__(256) void k_proj(
    const f16* __restrict__ Oh, const f16* __restrict__ woh,
    const float* __restrict__ bo, float* __restrict__ out)
{
    int bid = blockIdx.x;
    int tm = bid >> 3, tn = bid & 7;

    __shared__ f16 la[128 * 64];
    __shared__ f16 lb[128 * 64];

    int tid = threadIdx.x;
    int lane = tid & 63, wid = tid >> 6;
    int wr = wid >> 1, wc = wid & 1;
    int lm = lane & 15, qd = lane >> 4;

    f32x4 acc[4][4];
    #pragma unroll
    for (int i = 0; i < 4; i++)
        #pragma unroll
        for (int j = 0; j < 4; j++) acc[i][j] = (f32x4)0.0f;

    int m0 = tm * 128, n0 = tn * 128;

    for (int kt = 0; kt < 16; ++kt) {
        int k0 = kt * 64;
        __syncthreads();
        #pragma unroll
        for (int t = 0; t < 4; ++t) {
            int cid = tid + t * 256;
            int row = cid >> 3;
            int cg = cid & 7;
            int sw = cg ^ (row & 7);
            *(f16x8*)&la[row * 64 + sw * 8] =
                *(const f16x8*)&Oh[(long)(m0 + row) * 1024 + k0 + cg * 8];
            *(f16x8*)&lb[row * 64 + sw * 8] =
                *(const f16x8*)&woh[(long)(n0 + row) * 1024 + k0 + cg * 8];
        }
        __syncthreads();
        #pragma unroll
        for (int ks = 0; ks < 2; ++ks) {
            f16x8 af[4], bfr[4];
            #pragma unroll
            for (int i = 0; i < 4; i++) {
                int m = 64 * wr + 16 * i + lm;
                int g = (ks * 4 + qd) ^ (m & 7);
                af[i] = *(const f16x8*)&la[m * 64 + g * 8];
                int n = 64 * wc + 16 * i + lm;
                int g2 = (ks * 4 + qd) ^ (n & 7);
                bfr[i] = *(const f16x8*)&lb[n * 64 + g2 * 8];
            }
            #pragma unroll
            for (int i = 0; i < 4; i++)
                #pragma unroll
                for (int j = 0; j < 4; j++)
                    acc[i][j] = MFMA16(af[i], bfr[j], acc[i][j], 0, 0, 0);
        }
    }

    #pragma unroll
    for (int j = 0; j < 4; j++) {
        int n = n0 + 64 * wc + 16 * j + lm;
        float bb = bo[n];
        #pragma unroll
        for (int i = 0; i < 4; i++) {
            int mbase = m0 + 64 * wr + 16 * i + 4 * qd;
            #pragma unroll
            for (int r = 0; r < 4; ++r)
                out[(long)(mbase + r) * 1024 + n] = acc[i][j][r] + bb;
        }
    }
}

// ---------------- launch ----------------------------------------------------
extern "C" void kernel_launch(void* const* d_in, const int* in_sizes, int n_in,
                              void* d_out, int out_size, void* d_ws, size_t ws_size,
                              hipStream_t stream)
{
    const float* embed = (const float*)d_in[0];
    const float* key   = (const float*)d_in[1];
    const int*   mask  = (const int*)d_in[2];
    const float* Wq = (const float*)d_in[3];
    const float* bq = (const float*)d_in[4];
    const float* Wk = (const float*)d_in[5];
    const float* bk = (const float*)d_in[6];
    const float* Wv = (const float*)d_in[7];
    const float* bv = (const float*)d_in[8];
    const float* Wo = (const float*)d_in[9];
    const float* bo = (const float*)d_in[10];

    char* ws = (char*)d_ws;
    u64*   mb  = (u64*)(ws + 0);            // 1 MB
    f16*   xe  = (f16*)(ws + 1048576);      // 8 MB
    f16*   xk  = (f16*)(ws + 9437184);      // 8 MB
    f16*   wqh = (f16*)(ws + 17825792);     // 2 MB
    f16*   wkh = (f16*)(ws + 19922944);     // 2 MB
    f16*   wvh = (f16*)(ws + 22020096);     // 2 MB
    f16*   woh = (f16*)(ws + 24117248);     // 2 MB
    f16*   Qh  = (f16*)(ws + 26214400);     // 8 MB  [B][H][S][64]
    f16*   Kh  = (f16*)(ws + 34603008);     // 8 MB
    f16*   Vt  = (f16*)(ws + 42991616);     // 8 MB  [B][H][64][S]
    f16*   Oh  = (f16*)(ws + 51380224);     // 8 MB  [B*S][1024]
    float* out = (float*)d_out;

    k_convert<<<7168, 256, 0, stream>>>(embed, key, Wq, Wk, Wv, Wo, mask,
                                        xe, xk, wqh, wkh, wvh, woh, mb);
    k_qkv<<<768, 256, 0, stream>>>(xe, xk, wqh, wkh, wvh, bq, bk, bv, Qh, Kh, Vt);
    k_attn<<<1024, 256, 0, stream>>>(Qh, Kh, Vt, mb, Oh);
    k_proj<<<256, 256, 0, stream>>>(Oh, woh, bo, out);
}

// Round 8
// 294.397 us; speedup vs baseline: 1.3716x; 1.0056x over previous
//
#include <hip/hip_runtime.h>

// ---------------------------------------------------------------------------
// MultiheadAttention fwd, MI355X gfx950.
// B=2, S=2048, D=1024, H=16, DH=64.  fp16 compute, fp32 MFMA acc.
// R8: (1) attn ps stride 40 f16 -> bank-floor P bridge (was 8-way conflicted).
// (2) qkv/proj staging via global_load_lds width=16, linear LDS layout
//     (m97 pattern); MFMA fragment reads unswizzled.
// ---------------------------------------------------------------------------

typedef _Float16 f16;
typedef __attribute__((ext_vector_type(8))) _Float16 f16x8;
typedef __attribute__((ext_vector_type(4))) _Float16 f16x4;
typedef __attribute__((ext_vector_type(4))) float f32x4;
typedef unsigned long long u64;
typedef unsigned int u32;

#define MFMA16 __builtin_amdgcn_mfma_f32_16x16x32_f16

__device__ __forceinline__ void gload_lds16(const void* g, void* l) {
    __builtin_amdgcn_global_load_lds(
        (const __attribute__((address_space(1))) void*)g,
        (__attribute__((address_space(3))) void*)l, 16, 0, 0);
}

// ---------------- kernel 1: fp32 -> fp16 convert + mask packing ------------
__global__ __launch_bounds__(256) void k_convert(
    const float* __restrict__ embed, const float* __restrict__ key,
    const float* __restrict__ wq, const float* __restrict__ wk,
    const float* __restrict__ wv, const float* __restrict__ wo,
    const int* __restrict__ mask,
    f16* __restrict__ xe, f16* __restrict__ xk,
    f16* __restrict__ wqh, f16* __restrict__ wkh,
    f16* __restrict__ wvh, f16* __restrict__ woh,
    u64* __restrict__ bits)
{
    int bid = blockIdx.x;
    if (bid >= 6144) {
        int gw = (bid - 6144) * 4 + (threadIdx.x >> 6);   // row 0..4095
        int lane = threadIdx.x & 63;
        const int* row = mask + (long)gw * 2048;
        u64* outb = bits + (long)gw * 32;
        #pragma unroll 4
        for (int c = 0; c < 32; ++c) {
            int v = row[c * 64 + lane];
            u64 bm = __ballot(v != 0);
            if (lane == 0) outb[c] = bm;
        }
        return;
    }
    long g = (long)bid * 256 + threadIdx.x;   // one 8-float group
    const float* src; f16* dst; long off;
    if (g < 524288)       { src = embed; dst = xe; off = g; }
    else if (g < 1048576) { src = key;   dst = xk; off = g - 524288; }
    else {
        long t = g - 1048576; int wi = (int)(t >> 17); off = t & 131071;
        if (wi == 0)      { src = wq; dst = wqh; }
        else if (wi == 1) { src = wk; dst = wkh; }
        else if (wi == 2) { src = wv; dst = wvh; }
        else              { src = wo; dst = woh; }
    }
    const float4* s4 = (const float4*)src;
    float4 a = s4[off * 2], b = s4[off * 2 + 1];
    f16x8 o;
    o[0]=(f16)a.x; o[1]=(f16)a.y; o[2]=(f16)a.z; o[3]=(f16)a.w;
    o[4]=(f16)b.x; o[5]=(f16)b.y; o[6]=(f16)b.z; o[7]=(f16)b.w;
    *(f16x8*)(dst + off * 8) = o;
}

// ---------------- kernel 2: fused QKV GEMM (fp16 in, async staging) --------
__global__ __launch_bounds__(256) void k_qkv(
    const f16* __restrict__ xe, const f16* __restrict__ xk,
    const f16* __restrict__ wqh, const f16* __restrict__ wkh, const f16* __restrict__ wvh,
    const float* __restrict__ bq, const float* __restrict__ bk, const float* __restrict__ bv,
    f16* __restrict__ Qh, f16* __restrict__ Kh, f16* __restrict__ Vt)
{
    int bid = blockIdx.x;
    int which = bid >> 8;
    int rr_ = bid & 255;
    int tm = rr_ >> 3, tn = rr_ & 7;
    const f16* X = (which == 0) ? xe : xk;
    const f16* W = (which == 0) ? wqh : (which == 1) ? wkh : wvh;
    const float* bias = (which == 0) ? bq : (which == 1) ? bk : bv;

    __shared__ f16 smem[128 * 136];
    f16* la = smem;              // [128][64] linear
    f16* lb = smem + 128 * 64;   // [128][64] linear

    int tid = threadIdx.x;
    int lane = tid & 63, wid = tid >> 6;
    int wr = wid >> 1, wc = wid & 1;
    int lm = lane & 15, qd = lane >> 4;

    f32x4 acc[4][4];
    #pragma unroll
    for (int i = 0; i < 4; i++)
        #pragma unroll
        for (int j = 0; j < 4; j++) acc[i][j] = (f32x4)0.0f;

    int m0 = tm * 128, n0 = tn * 128;
    int wbase8 = (tid & 192) * 8;      // wave's lane0 chunk * 8 f16

    for (int kt = 0; kt < 16; ++kt) {
        int k0 = kt * 64;
        __syncthreads();
        #pragma unroll
        for (int t = 0; t < 4; ++t) {
            int cid = tid + t * 256;          // 0..1023 16B chunks
            int row = cid >> 3, cg = cid & 7;
            f16* da = la + t * 2048 + wbase8;     // wave-uniform base
            f16* db = lb + t * 2048 + wbase8;
            gload_lds16(&X[(long)(m0 + row) * 1024 + k0 + cg * 8], da);
            gload_lds16(&W[(long)(n0 + row) * 1024 + k0 + cg * 8], db);
        }
        __syncthreads();
        #pragma unroll
        for (int ks = 0; ks < 2; ++ks) {
            f16x8 af[4], bfr[4];
            #pragma unroll
            for (int i = 0; i < 4; i++) {
                int m = 64 * wr + 16 * i + lm;
                af[i] = *(const f16x8*)&la[m * 64 + ks * 32 + qd * 8];
                int n = 64 * wc + 16 * i + lm;
                bfr[i] = *(const f16x8*)&lb[n * 64 + ks * 32 + qd * 8];
            }
            #pragma unroll
            for (int i = 0; i < 4; i++)
                #pragma unroll
                for (int j = 0; j < 4; j++)
                    acc[i][j] = MFMA16(af[i], bfr[j], acc[i][j], 0, 0, 0);
        }
    }

    if (which == 2) {
        // V: direct transposed store [B][H][64][S], b64 along s
        #pragma unroll
        for (int j = 0; j < 4; j++) {
            int n = n0 + 64 * wc + 16 * j + lm;
            float bb = bias[n];
            int h = n >> 6, d = n & 63;
            #pragma unroll
            for (int i = 0; i < 4; i++) {
                int mbase = m0 + 64 * wr + 16 * i + 4 * qd;
                f16x4 pk;
                #pragma unroll
                for (int r = 0; r < 4; ++r) pk[r] = (f16)(acc[i][j][r] + bb);
                int b = mbase >> 11, s = mbase & 2047;
                *(f16x4*)&Vt[(((long)(b * 16 + h)) * 64 + d) * 2048 + s] = pk;
            }
        }
    } else {
        // Q/K: LDS bounce -> coalesced b128 row stores
        f16* dst = (which == 0) ? Qh : Kh;
        __syncthreads();
        #pragma unroll
        for (int j = 0; j < 4; j++) {
            int col = 64 * wc + 16 * j + lm;
            float bb = bias[n0 + col];
            #pragma unroll
            for (int i = 0; i < 4; i++) {
                int row = 64 * wr + 16 * i + 4 * qd;
                #pragma unroll
                for (int r = 0; r < 4; ++r)
                    smem[(row + r) * 136 + col] = (f16)(acc[i][j][r] + bb);
            }
        }
        __syncthreads();
        #pragma unroll
        for (int t = 0; t < 8; ++t) {
            int ci = tid + t * 256;            // 0..2047
            int row = ci >> 4, cg = ci & 15;
            f16x8 v = *(const f16x8*)&smem[row * 136 + cg * 8];
            int m = m0 + row;
            int b = m >> 11, s = m & 2047;
            int h = (n0 >> 6) + (cg >> 3);
            int d0 = (cg & 7) * 8;
            *(f16x8*)&dst[(((long)(b * 16 + h)) * 2048 + s) * 64 + d0] = v;
        }
    }
}

// ---------------- kernel 3: flash attention, single pass -------------------
// grid 1024, 256 thr (4 waves x 16 q). q-tile 64. XCD swizzle for K/V L2.
// Fixed-max softmax (M=4); interleaved QK->softmax->PV per 32-key chunk.
// ps stride 40 f16: bank-floor b64 writes / b128 reads, 16B-aligned.
__global__ __launch_bounds__(256, 4) void k_attn(
    const f16* __restrict__ Qh, const f16* __restrict__ Kh, const f16* __restrict__ Vt,
    const u64* __restrict__ mbits, f16* __restrict__ O)
{
    int bid = blockIdx.x;
    int x = bid & 7, j = bid >> 3;
    int bh = ((j >> 5) << 3) + x;        // 0..31
    int qt = j & 31;                     // 0..31
    int b = bh >> 4, h = bh & 15;
    int q0 = qt * 64;

    const f16* Qg = Qh + ((long)bh) * 2048 * 64;
    const f16* Kg = Kh + ((long)bh) * 2048 * 64;
    const f16* Vg = Vt + ((long)bh) * 64 * 2048;

    __shared__ f16 ks[128 * 64];       // 16 KB  K tile [key][d]
    __shared__ f16 vs[64 * 128];       // 16 KB  V^T tile [d][key]
    __shared__ f16 ps[4][16 * 40];     //  5 KB  per-wave P [q16][stride 40]

    int tid = threadIdx.x, lane = tid & 63, wid = tid >> 6;
    int lm = lane & 15, qd = lane >> 4;

    int qrow = q0 + 16 * wid + lm;
    const u64* Mrow = mbits + ((long)(b * 2048) + qrow) * 32;

    f16x8 aq[2];
    #pragma unroll
    for (int ksi = 0; ksi < 2; ++ksi)
        aq[ksi] = *(const f16x8*)&Qg[(long)qrow * 64 + ksi * 32 + qd * 8];

    f32x4 oacc[4], lacc;
    #pragma unroll
    for (int c = 0; c < 4; c++) oacc[c] = (f32x4)0.0f;
    lacc = (f32x4)0.0f;
    f16x8 vone;
    #pragma unroll
    for (int jj = 0; jj < 8; jj++) vone[jj] = (f16)1.0f;

    // p = exp2(qk*c1 - |dist|*c2 - c3);  M = 4 fixed softmax max
    const float c1 = 0.0450842252f;                                   // (1/32)*log2e
    float negc2 = -__builtin_amdgcn_exp2f(-0.5f * (float)(h + 1)) * c1;
    const float c3 = 5.7707801634f;                                   // 4*log2e

    for (int kt = 0; kt < 16; ++kt) {
        int k0 = kt * 128;
        __syncthreads();
        #pragma unroll
        for (int t = 0; t < 4; ++t) {
            int cid = tid + t * 256;          // 0..1023 16B chunks
            int row = cid >> 3, cg = cid & 7;
            int sw = cg ^ (row & 7);
            *(f16x8*)&ks[row * 64 + sw * 8] =
                *(const f16x8*)&Kg[(long)(k0 + row) * 64 + cg * 8];
            int vrow = cid >> 4, vg = cid & 15;
            int vsw = vg ^ (vrow & 7);
            *(f16x8*)&vs[vrow * 128 + vsw * 8] =
                *(const f16x8*)&Vg[(long)vrow * 2048 + k0 + vg * 8];
        }
        __syncthreads();

        u64 w0 = Mrow[kt * 2], w1 = Mrow[kt * 2 + 1];
        float qmk = (float)(qrow - k0);

        #pragma unroll
        for (int t = 0; t < 4; ++t) {
            // ---- QK for key chunk [32t, 32t+32) ----
            f32x4 sacc0 = (f32x4)0.0f, sacc1 = (f32x4)0.0f;
            #pragma unroll
            for (int ksi = 0; ksi < 2; ++ksi) {
                int kr0 = 32 * t + lm;
                int g0 = (ksi * 4 + qd) ^ (kr0 & 7);
                f16x8 ak0 = *(const f16x8*)&ks[kr0 * 64 + g0 * 8];
                sacc0 = MFMA16(ak0, aq[ksi], sacc0, 0, 0, 0);
                int kr1 = 32 * t + 16 + lm;
                int g1 = (ksi * 4 + qd) ^ (kr1 & 7);
                f16x8 ak1 = *(const f16x8*)&ks[kr1 * 64 + g1 * 8];
                sacc1 = MFMA16(ak1, aq[ksi], sacc1, 0, 0, 0);
            }
            // ---- softmax for the 2 16-key groups ----
            #pragma unroll
            for (int cc = 0; cc < 2; ++cc) {
                const f32x4& sa = cc ? sacc1 : sacc0;
                int c = 2 * t + cc;
                u32 nib = (u32)(((c < 4) ? w0 : w1) >> (16 * (c & 3) + 4 * qd)) & 15u;
                float qmkc = qmk - (float)(16 * c + 4 * qd);
                f16x4 pk;
                #pragma unroll
                for (int r = 0; r < 4; ++r) {
                    float t2 = fmaf(sa[r], c1, -c3);
                    float u = fmaf(fabsf(qmkc - (float)r), negc2, t2);
                    u = ((nib >> r) & 1u) ? u : -1e30f;
                    pk[r] = (f16)__builtin_amdgcn_exp2f(u);
                }
                *(f16x4*)&ps[wid][lm * 40 + cc * 16 + 4 * qd] = pk;
            }
            // ---- PV for this 32-key chunk (same-wave LDS round trip) ----
            f16x8 pa = *(const f16x8*)&ps[wid][lm * 40 + qd * 8];
            #pragma unroll
            for (int cc2 = 0; cc2 < 4; ++cc2) {
                int d = 16 * cc2 + lm;
                int g = (t * 4 + qd) ^ (d & 7);
                f16x8 vb = *(const f16x8*)&vs[d * 128 + g * 8];
                oacc[cc2] = MFMA16(pa, vb, oacc[cc2], 0, 0, 0);
            }
            lacc = MFMA16(pa, vone, lacc, 0, 0, 0);
        }
    }

    // epilogue: O[b][q][h*64+d] fp16
    #pragma unroll
    for (int r = 0; r < 4; ++r) {
        float linv = 1.0f / fmaxf(lacc[r], 1e-30f);
        long rowbase = ((long)(b * 2048 + q0 + 16 * wid + 4 * qd + r)) * 1024 + h * 64;
        #pragma unroll
        for (int cc = 0; cc < 4; ++cc)
            O[rowbase + 16 * cc + lm] = (f16)(oacc[cc][r] * linv);
    }
}

// ---------------- kernel 4: output projection (async staging) --------------
__global__ __launch_bounds__(256) void k_proj(
    const f16* __restrict__ Oh, const f16* __restrict__ woh,
    const float* __restrict__ bo, float* __restrict__ out)
{
    int bid = blockIdx.x;
    int tm = bid >> 3, tn = bid & 7;

    __shared__ f16 la[128 * 64];   // linear
    __shared__ f16 lb[128 * 64];   // linear

    int tid = threadIdx.x;
    int lane = tid & 63, wid = tid >> 6;
    int wr = wid >> 1, wc = wid & 1;
    int lm = lane & 15, qd = lane >> 4;

    f32x4 acc[4][4];
    #pragma unroll
    for (int i = 0; i < 4; i++)
        #pragma unroll
        for (int j = 0; j < 4; j++) acc[i][j] = (f32x4)0.0f;

    int m0 = tm * 128, n0 = tn * 128;
    int wbase8 = (tid & 192) * 8;

    for (int kt = 0; kt < 16; ++kt) {
        int k0 = kt * 64;
        __syncthreads();
        #pragma unroll
        for (int t = 0; t < 4; ++t) {
            int cid = tid + t * 256;
            int row = cid >> 3, cg = cid & 7;
            gload_lds16(&Oh[(long)(m0 + row) * 1024 + k0 + cg * 8],
                        la + t * 2048 + wbase8);
            gload_lds16(&woh[(long)(n0 + row) * 1024 + k0 + cg * 8],
                        lb + t * 2048 + wbase8);
        }
        __syncthreads();
        #pragma unroll
        for (int ks = 0; ks < 2; ++ks) {
            f16x8 af[4], bfr[4];
            #pragma unroll
            for (int i = 0; i < 4; i++) {
                int m = 64 * wr + 16 * i + lm;
                af[i] = *(const f16x8*)&la[m * 64 + ks * 32 + qd * 8];
                int n = 64 * wc + 16 * i + lm;
                bfr[i] = *(const f16x8*)&lb[n * 64 + ks * 32 + qd * 8];
            }
            #pragma unroll
            for (int i = 0; i < 4; i++)
                #pragma unroll
                for (int j = 0; j < 4; j++)
                    acc[i][j] = MFMA16(af[i], bfr[j], acc[i][j], 0, 0, 0);
        }
    }

    #pragma unroll
    for (int j = 0; j < 4; j++) {
        int n = n0 + 64 * wc + 16 * j + lm;
        float bb = bo[n];
        #pragma unroll
        for (int i = 0; i < 4; i++) {
            int mbase = m0 + 64 * wr + 16 * i + 4 * qd;
            #pragma unroll
            for (int r = 0; r < 4; ++r)
                out[(long)(mbase + r) * 1024 + n] = acc[i][j][r] + bb;
        }
    }
}

// ---------------- launch ----------------------------------------------------
extern "C" void kernel_launch(void* const* d_in, const int* in_sizes, int n_in,
                              void* d_out, int out_size, void* d_ws, size_t ws_size,
                              hipStream_t stream)
{
    const float* embed = (const float*)d_in[0];
    const float* key   = (const float*)d_in[1];
    const int*   mask  = (const int*)d_in[2];
    const float* Wq = (const float*)d_in[3];
    const float* bq = (const float*)d_in[4];
    const float* Wk = (const float*)d_in[5];
    const float* bk = (const float*)d_in[6];
    const float* Wv = (const float*)d_in[7];
    const float* bv = (const float*)d_in[8];
    const float* Wo = (const float*)d_in[9];
    const float* bo = (const float*)d_in[10];

    char* ws = (char*)d_ws;
    u64*   mb  = (u64*)(ws + 0);            // 1 MB
    f16*   xe  = (f16*)(ws + 1048576);      // 8 MB
    f16*   xk  = (f16*)(ws + 9437184);      // 8 MB
    f16*   wqh = (f16*)(ws + 17825792);     // 2 MB
    f16*   wkh = (f16*)(ws + 19922944);     // 2 MB
    f16*   wvh = (f16*)(ws + 22020096);     // 2 MB
    f16*   woh = (f16*)(ws + 24117248);     // 2 MB
    f16*   Qh  = (f16*)(ws + 26214400);     // 8 MB  [B][H][S][64]
    f16*   Kh  = (f16*)(ws + 34603008);     // 8 MB
    f16*   Vt  = (f16*)(ws + 42991616);     // 8 MB  [B][H][64][S]
    f16*   Oh  = (f16*)(ws + 51380224);     // 8 MB  [B*S][1024]
    float* out = (float*)d_out;

    k_convert<<<7168, 256, 0, stream>>>(embed, key, Wq, Wk, Wv, Wo, mask,
                                        xe, xk, wqh, wkh, wvh, woh, mb);
    k_qkv<<<768, 256, 0, stream>>>(xe, xk, wqh, wkh, wvh, bq, bk, bv, Qh, Kh, Vt);
    k_attn<<<1024, 256, 0, stream>>>(Qh, Kh, Vt, mb, Oh);
    k_proj<<<256, 256, 0, stream>>>(Oh, woh, bo, out);
}